// Round 6
// baseline (83.836 us; speedup 1.0000x reference)
//
#include <hip/hip_runtime.h>
#include <hip/hip_cooperative_groups.h>
#include <math.h>

namespace cg = cooperative_groups;

static constexpr int B  = 4096;
static constexpr int L  = 4096;
static constexpr int ROWS_PER_BLK = 4;
static constexpr int NBLK = B / ROWS_PER_BLK;   // 1024 blocks, 256 thr each
// 1024*256 = 262144 = 16384 x-values * 16 powers (exact)

typedef float f4 __attribute__((ext_vector_type(4)));

__device__ __constant__ float c_ps_powers[16] = {
    -5.0f, -4.0f, -3.0f, -2.0f, -1.5f, -1.0f, -0.5f, 0.0f,
     0.5f,  2.0f,  0.33333334f, 3.0f, 0.25f, 4.0f, 0.2f, 5.0f};

__device__ __constant__ float c_poly[5] = {2.0f, 5.0f, 8.0f, 11.0f, 14.0f};

// hardware transcendentals: v_log_f32 (log2 x), v_exp_f32 (2^x)
__device__ __forceinline__ float hw_log2(float x) { return __builtin_amdgcn_logf(x); }
__device__ __forceinline__ float hw_exp2(float x) { return __builtin_amdgcn_exp2f(x); }

__device__ __forceinline__ float poly_eval(float e, float c0, float c1,
                                           float c2, float c3, float c4) {
    const float e3 = e * e * e;
    float w   = e;             // e^1
    float acc = c0 * w;
    w *= e3;                   // e^4
    acc = fmaf(c1, w, acc);
    w *= e3;                   // e^7
    acc = fmaf(c2, w, acc);
    w *= e3;                   // e^10
    acc = fmaf(c3, w, acc);
    w *= e3;                   // e^13
    acc = fmaf(c4, w, acc);
    return acc;
}

// ---------------------------------------------------------------------------
// Single cooperative kernel:
//  A) stats partials: thread g -> x = pp[g>>4], power (g&15); f64 block tree
//  B) grid.sync; every block redundantly reduces the 1024 partials (L2-hot,
//     deterministic, identical result everywhere)
//  C) 4 rows/block: features+MLP -> 5 scaled coefs in LDS, then f4 stream
// ---------------------------------------------------------------------------
__global__ __launch_bounds__(256, 4)
void k_all(const float* __restrict__ pp,  const float* __restrict__ eta,
           const float* __restrict__ W1,  const float* __restrict__ b1,
           const float* __restrict__ W2,  const float* __restrict__ b2,
           double* __restrict__ part, float* __restrict__ out) {
    cg::grid_group grid = cg::this_grid();
    const int tid = threadIdx.x;
    const int blk = blockIdx.x;

    __shared__ double sh_s[256];
    __shared__ double sh_s2[256];
    __shared__ float  sh_r[ROWS_PER_BLK][64];
    __shared__ float  sh_h[ROWS_PER_BLK][32];
    __shared__ float  sh_c[ROWS_PER_BLK][8];

    // ---------- phase A: per-block stats partials ----------
    {
        const int g = blk * 256 + tid;              // 0 .. 262143
        const float x  = pp[g >> 4];
        const float t  = hw_exp2(c_ps_powers[g & 15] * hw_log2(x));
        sh_s[tid]  = (double)t;
        sh_s2[tid] = (double)t * (double)t;
    }
    __syncthreads();
    for (int off = 128; off > 0; off >>= 1) {
        if (tid < off) {
            sh_s[tid]  += sh_s[tid + off];
            sh_s2[tid] += sh_s2[tid + off];
        }
        __syncthreads();
    }
    if (tid == 0) {
        part[blk]        = sh_s[0];
        part[NBLK + blk] = sh_s2[0];
    }

    grid.sync();

    // ---------- phase B: redundant final reduction (identical per block) ----
    {
        double s = 0.0, s2 = 0.0;
        #pragma unroll
        for (int k = 0; k < NBLK / 256; ++k) {
            s  += part[tid + k * 256];
            s2 += part[NBLK + tid + k * 256];
        }
        sh_s[tid] = s; sh_s2[tid] = s2;
    }
    __syncthreads();
    for (int off = 128; off > 0; off >>= 1) {
        if (tid < off) {
            sh_s[tid]  += sh_s[tid + off];
            sh_s2[tid] += sh_s2[tid + off];
        }
        __syncthreads();
    }
    const double n      = 262144.0;
    const double mean_d = sh_s[0] / n;
    const double var    = (sh_s2[0] - n * mean_d * mean_d) / (n - 1.0);
    const float  mean    = (float)mean_d;
    const float  inv_std = (float)(1.0 / sqrt(var));

    // ---------- phase C: coefficients for 4 rows, then stream ----------
    const int row0 = blk * ROWS_PER_BLK;

    {   // features: (row r = tid>>6, feature j = tid&63)
        const int r = tid >> 6;
        const int j = tid & 63;
        const float x = pp[(row0 + r) * 4 + (j >> 4)];
        const float t = hw_exp2(c_ps_powers[j & 15] * hw_log2(x));
        sh_r[r][j] = fmaxf((t - mean) * inv_std, 0.0f);
    }
    __syncthreads();

    if (tid < 128) {   // hidden layer: (row r = tid>>5, neuron h = tid&31)
        const int r = tid >> 5;
        const int h = tid & 31;
        float acc = b1[h];
        const float* w = W1 + h * 64;
        #pragma unroll
        for (int j = 0; j < 64; ++j) acc = fmaf(sh_r[r][j], w[j], acc);
        sh_h[r][h] = acc;
    }
    __syncthreads();

    if (tid < 32) {    // output layer: (row r = tid>>3, coef k = tid&7)
        const int r = tid >> 3;
        const int k = tid & 7;
        if (k < 5) {
            float acc = b2[k];
            const float* w = W2 + k * 32;
            #pragma unroll
            for (int o = 0; o < 32; ++o) acc = fmaf(sh_h[r][o], w[o], acc);
            sh_c[r][k] = acc * c_poly[k];
        }
    }
    __syncthreads();

    #pragma unroll
    for (int rr = 0; rr < ROWS_PER_BLK; ++rr) {
        const float c0 = sh_c[rr][0], c1 = sh_c[rr][1], c2 = sh_c[rr][2],
                    c3 = sh_c[rr][3], c4 = sh_c[rr][4];
        const f4* ep = reinterpret_cast<const f4*>(eta + (size_t)(row0 + rr) * L);
        f4*       op = reinterpret_cast<f4*>(out + (size_t)(row0 + rr) * L);
        #pragma unroll
        for (int it = 0; it < L / 4 / 256; ++it) {
            const int i = tid + it * 256;
            const f4 e = ep[i];
            f4 r;
            r.x = poly_eval(e.x, c0, c1, c2, c3, c4);
            r.y = poly_eval(e.y, c0, c1, c2, c3, c4);
            r.z = poly_eval(e.z, c0, c1, c2, c3, c4);
            r.w = poly_eval(e.w, c0, c1, c2, c3, c4);
            op[i] = r;
        }
    }
}

// ---------------------------------------------------------------------------
extern "C" void kernel_launch(void* const* d_in, const int* in_sizes, int n_in,
                              void* d_out, int out_size, void* d_ws, size_t ws_size,
                              hipStream_t stream) {
    const float* pp  = (const float*)d_in[0];   // [B,4]
    const float* eta = (const float*)d_in[1];   // [B,L]
    const float* W1  = (const float*)d_in[2];   // [32,64]
    const float* b1  = (const float*)d_in[3];   // [32]
    const float* W2  = (const float*)d_in[4];   // [5,32]
    const float* b2  = (const float*)d_in[5];   // [5]
    float* out   = (float*)d_out;
    double* part = (double*)d_ws;               // 2*NBLK doubles (16 KB)

    void* args[] = {(void*)&pp, (void*)&eta, (void*)&W1, (void*)&b1,
                    (void*)&W2, (void*)&b2, (void*)&part, (void*)&out};
    hipLaunchCooperativeKernel((const void*)k_all, dim3(NBLK), dim3(256),
                               args, 0, stream);
}

// Round 7
// 41.269 us; speedup vs baseline: 2.0315x; 2.0315x over previous
//
#include <hip/hip_runtime.h>
#include <math.h>

static constexpr int B  = 4096;
static constexpr int L  = 4096;
static constexpr int NX = B * 4;            // 16384 physical-param scalars
static constexpr int STATS_THREADS = 1024;

typedef float f4 __attribute__((ext_vector_type(4)));

__device__ __constant__ float c_ps_powers[16] = {
    -5.0f, -4.0f, -3.0f, -2.0f, -1.5f, -1.0f, -0.5f, 0.0f,
     0.5f,  2.0f,  0.33333334f, 3.0f, 0.25f, 4.0f, 0.2f, 5.0f};

__device__ __constant__ float c_poly[5] = {2.0f, 5.0f, 8.0f, 11.0f, 14.0f};

// hardware transcendentals: v_log_f32 (log2 x), v_exp_f32 (2^x)
__device__ __forceinline__ float hw_log2(float x) { return __builtin_amdgcn_logf(x); }
__device__ __forceinline__ float hw_exp2(float x) { return __builtin_amdgcn_exp2f(x); }

// ---------------------------------------------------------------------------
// Kernel 1 (single block): mean and 1/std (ddof=1) of t = pp ** PS_POWERS.
// stats[0] = mean, stats[1] = inv_std
// ---------------------------------------------------------------------------
__global__ __launch_bounds__(STATS_THREADS)
void k_stats(const float* __restrict__ pp, float* __restrict__ stats) {
    const int tid = threadIdx.x;
    const f4* pp4 = reinterpret_cast<const f4*>(pp);
    double s = 0.0, s2 = 0.0;
    #pragma unroll
    for (int k = 0; k < NX / 4 / STATS_THREADS; ++k) {
        const f4 xv = pp4[tid + k * STATS_THREADS];
        #pragma unroll
        for (int c = 0; c < 4; ++c) {
            const float lx = hw_log2(xv[c]);
            float sf = 0.0f, sf2 = 0.0f;
            #pragma unroll
            for (int p = 0; p < 16; ++p) {
                const float t = hw_exp2(c_ps_powers[p] * lx);
                sf  += t;
                sf2 = fmaf(t, t, sf2);
            }
            s  += (double)sf;
            s2 += (double)sf2;
        }
    }
    __shared__ double sh_s[STATS_THREADS];
    __shared__ double sh_s2[STATS_THREADS];
    sh_s[tid] = s; sh_s2[tid] = s2;
    __syncthreads();
    for (int off = STATS_THREADS >> 1; off > 0; off >>= 1) {
        if (tid < off) {
            sh_s[tid]  += sh_s[tid + off];
            sh_s2[tid] += sh_s2[tid + off];
        }
        __syncthreads();
    }
    if (tid == 0) {
        const double n    = (double)(B * 64);
        const double mean = sh_s[0] / n;
        const double var  = (sh_s2[0] - n * mean * mean) / (n - 1.0);
        stats[0] = (float)mean;
        stats[1] = (float)(1.0 / sqrt(var));
    }
}

// ---------------------------------------------------------------------------
// Kernel 2: one row per block. The 4 eta float4 loads are issued FIRST so
// their HBM latency hides under the MLP prologue (the compiler drains
// vmcnt(0) at the first __syncthreads, so data is in-register by the time
// the prologue finishes). Then features+MLP in LDS, then batched
// compute+store:
//   dy = c0'*e + c1'*e^4 + c2'*e^7 + c3'*e^10 + c4'*e^13   (ck' = ck * p_k)
// ---------------------------------------------------------------------------
__device__ __forceinline__ float poly_eval(float e, float c0, float c1,
                                           float c2, float c3, float c4) {
    const float e3 = e * e * e;
    float w   = e;             // e^1
    float acc = c0 * w;
    w *= e3;                   // e^4
    acc = fmaf(c1, w, acc);
    w *= e3;                   // e^7
    acc = fmaf(c2, w, acc);
    w *= e3;                   // e^10
    acc = fmaf(c3, w, acc);
    w *= e3;                   // e^13
    acc = fmaf(c4, w, acc);
    return acc;
}

__device__ __forceinline__ f4 poly_eval4(f4 e, float c0, float c1,
                                         float c2, float c3, float c4) {
    f4 r;
    r.x = poly_eval(e.x, c0, c1, c2, c3, c4);
    r.y = poly_eval(e.y, c0, c1, c2, c3, c4);
    r.z = poly_eval(e.z, c0, c1, c2, c3, c4);
    r.w = poly_eval(e.w, c0, c1, c2, c3, c4);
    return r;
}

__global__ __launch_bounds__(256)
void k_main(const float* __restrict__ pp,  const float* __restrict__ eta,
            const float* __restrict__ W1,  const float* __restrict__ b1,
            const float* __restrict__ W2,  const float* __restrict__ b2,
            const float* __restrict__ stats, float* __restrict__ out) {
    const int row = blockIdx.x;
    const int tid = threadIdx.x;

    // ---- issue all global loads up front (latency hides under prologue) ----
    const f4* ep = reinterpret_cast<const f4*>(eta + (size_t)row * L);
    f4*       op = reinterpret_cast<f4*>(out + (size_t)row * L);
    const f4 e0 = ep[tid];
    const f4 e1 = ep[tid + 256];
    const f4 e2 = ep[tid + 512];
    const f4 e3 = ep[tid + 768];

    __shared__ float sh_r[64];   // relu(norm) features
    __shared__ float sh_h[32];   // hidden layer
    __shared__ float sh_c[8];    // scaled coefficients

    if (tid < 64) {
        const float mean    = stats[0];
        const float inv_std = stats[1];
        const float x = pp[(row << 2) + (tid >> 4)];
        const float t = hw_exp2(c_ps_powers[tid & 15] * hw_log2(x));
        sh_r[tid] = fmaxf((t - mean) * inv_std, 0.0f);
    }
    __syncthreads();

    if (tid < 32) {
        float acc = b1[tid];
        const float* w = W1 + tid * 64;
        #pragma unroll
        for (int j = 0; j < 64; ++j) acc = fmaf(sh_r[j], w[j], acc);
        sh_h[tid] = acc;
    }
    __syncthreads();

    if (tid < 5) {
        float acc = b2[tid];
        const float* w = W2 + tid * 32;
        #pragma unroll
        for (int o = 0; o < 32; ++o) acc = fmaf(sh_h[o], w[o], acc);
        sh_c[tid] = acc * c_poly[tid];
    }
    __syncthreads();

    const float c0 = sh_c[0], c1 = sh_c[1], c2 = sh_c[2],
                c3 = sh_c[3], c4 = sh_c[4];

    // ---- batched compute + store (data already in registers) ----
    op[tid]       = poly_eval4(e0, c0, c1, c2, c3, c4);
    op[tid + 256] = poly_eval4(e1, c0, c1, c2, c3, c4);
    op[tid + 512] = poly_eval4(e2, c0, c1, c2, c3, c4);
    op[tid + 768] = poly_eval4(e3, c0, c1, c2, c3, c4);
}

// ---------------------------------------------------------------------------
extern "C" void kernel_launch(void* const* d_in, const int* in_sizes, int n_in,
                              void* d_out, int out_size, void* d_ws, size_t ws_size,
                              hipStream_t stream) {
    const float* pp  = (const float*)d_in[0];   // [B,4]
    const float* eta = (const float*)d_in[1];   // [B,L]
    const float* W1  = (const float*)d_in[2];   // [32,64]
    const float* b1  = (const float*)d_in[3];   // [32]
    const float* W2  = (const float*)d_in[4];   // [5,32]
    const float* b2  = (const float*)d_in[5];   // [5]
    float* out = (float*)d_out;

    float* stats = (float*)d_ws;                // 2 floats

    k_stats<<<1, STATS_THREADS, 0, stream>>>(pp, stats);
    k_main<<<B, 256, 0, stream>>>(pp, eta, W1, b1, W2, b2, stats, out);
}

// Round 8
// 33.780 us; speedup vs baseline: 2.4819x; 1.2217x over previous
//
#include <hip/hip_runtime.h>
#include <math.h>

static constexpr int B  = 4096;
static constexpr int L  = 4096;
static constexpr int NPART = 64;           // stats blocks; 64*256 = 16384 x-values

typedef float f4 __attribute__((ext_vector_type(4)));

__device__ __constant__ float c_ps_powers[16] = {
    -5.0f, -4.0f, -3.0f, -2.0f, -1.5f, -1.0f, -0.5f, 0.0f,
     0.5f,  2.0f,  0.33333334f, 3.0f, 0.25f, 4.0f, 0.2f, 5.0f};

__device__ __constant__ float c_poly[5] = {2.0f, 5.0f, 8.0f, 11.0f, 14.0f};

// hardware transcendentals: v_log_f32 (log2 x), v_exp_f32 (2^x)
__device__ __forceinline__ float hw_log2(float x) { return __builtin_amdgcn_logf(x); }
__device__ __forceinline__ float hw_exp2(float x) { return __builtin_amdgcn_exp2f(x); }

// ---------------------------------------------------------------------------
// Kernel 1: 64 blocks x 256 threads — one x-value per thread.
// part[0..63] = block sums, part[64..127] = block sumsqs (f64).
// ---------------------------------------------------------------------------
__global__ __launch_bounds__(256)
void k_part(const float* __restrict__ pp, double* __restrict__ part) {
    const int tid = threadIdx.x;
    const int g   = blockIdx.x * 256 + tid;       // 0 .. 16383
    const float lx = hw_log2(pp[g]);
    float sf = 0.0f, sf2 = 0.0f;
    #pragma unroll
    for (int p = 0; p < 16; ++p) {
        const float t = hw_exp2(c_ps_powers[p] * lx);
        sf  += t;
        sf2 = fmaf(t, t, sf2);
    }
    __shared__ double sh_s[256];
    __shared__ double sh_s2[256];
    sh_s[tid]  = (double)sf;
    sh_s2[tid] = (double)sf2;
    __syncthreads();
    for (int off = 128; off > 0; off >>= 1) {
        if (tid < off) {
            sh_s[tid]  += sh_s[tid + off];
            sh_s2[tid] += sh_s2[tid + off];
        }
        __syncthreads();
    }
    if (tid == 0) {
        part[blockIdx.x]         = sh_s[0];
        part[NPART + blockIdx.x] = sh_s2[0];
    }
}

// ---------------------------------------------------------------------------
// Kernel 2: one row per block.
//  - eta float4 loads issued first (latency hides under prologue)
//  - wave 0 redundantly shuffle-reduces the 128 partials (L2-hot, identical
//    in every block, deterministic) -> mean, inv_std
//  - features + MLP -> 5 scaled coefficients in LDS
//  - batched compute + store:
//      dy = c0'*e + c1'*e^4 + c2'*e^7 + c3'*e^10 + c4'*e^13  (ck' = ck*p_k)
// ---------------------------------------------------------------------------
__device__ __forceinline__ float poly_eval(float e, float c0, float c1,
                                           float c2, float c3, float c4) {
    const float e3 = e * e * e;
    float w   = e;             // e^1
    float acc = c0 * w;
    w *= e3;                   // e^4
    acc = fmaf(c1, w, acc);
    w *= e3;                   // e^7
    acc = fmaf(c2, w, acc);
    w *= e3;                   // e^10
    acc = fmaf(c3, w, acc);
    w *= e3;                   // e^13
    acc = fmaf(c4, w, acc);
    return acc;
}

__device__ __forceinline__ f4 poly_eval4(f4 e, float c0, float c1,
                                         float c2, float c3, float c4) {
    f4 r;
    r.x = poly_eval(e.x, c0, c1, c2, c3, c4);
    r.y = poly_eval(e.y, c0, c1, c2, c3, c4);
    r.z = poly_eval(e.z, c0, c1, c2, c3, c4);
    r.w = poly_eval(e.w, c0, c1, c2, c3, c4);
    return r;
}

__global__ __launch_bounds__(256)
void k_main(const float* __restrict__ pp,  const float* __restrict__ eta,
            const float* __restrict__ W1,  const float* __restrict__ b1,
            const float* __restrict__ W2,  const float* __restrict__ b2,
            const double* __restrict__ part, float* __restrict__ out) {
    const int row = blockIdx.x;
    const int tid = threadIdx.x;

    // ---- issue all global loads up front ----
    const f4* ep = reinterpret_cast<const f4*>(eta + (size_t)row * L);
    f4*       op = reinterpret_cast<f4*>(out + (size_t)row * L);
    const f4 e0 = ep[tid];
    const f4 e1 = ep[tid + 256];
    const f4 e2 = ep[tid + 512];
    const f4 e3 = ep[tid + 768];

    __shared__ float sh_r[64];   // relu(norm) features
    __shared__ float sh_h[32];   // hidden layer
    __shared__ float sh_c[8];    // scaled coefficients
    __shared__ float sh_stat[2]; // mean, inv_std

    // ---- wave 0: finalize stats + compute features ----
    if (tid < 64) {
        // shuffle-reduce the 128 partials across the wave (deterministic)
        double s  = part[tid];
        double s2 = part[NPART + tid];
        #pragma unroll
        for (int m = 32; m > 0; m >>= 1) {
            s  += __shfl_xor(s,  m, 64);
            s2 += __shfl_xor(s2, m, 64);
        }
        if (tid == 0) {
            const double n    = 262144.0;
            const double mean = s / n;
            const double var  = (s2 - n * mean * mean) / (n - 1.0);
            sh_stat[0] = (float)mean;
            sh_stat[1] = (float)(1.0 / sqrt(var));
        }
        // features (independent of stats until the normalize)
        const float x = pp[(row << 2) + (tid >> 4)];
        const float t = hw_exp2(c_ps_powers[tid & 15] * hw_log2(x));
        const float mean    = __shfl(sh_stat[0], 0, 64);  // broadcast via lane0? no — use shared
        (void)mean;
        sh_r[tid] = t;            // store raw t; normalize after barrier
    }
    __syncthreads();

    if (tid < 64) {
        sh_r[tid] = fmaxf((sh_r[tid] - sh_stat[0]) * sh_stat[1], 0.0f);
    }
    __syncthreads();

    if (tid < 32) {
        float acc = b1[tid];
        const float* w = W1 + tid * 64;
        #pragma unroll
        for (int j = 0; j < 64; ++j) acc = fmaf(sh_r[j], w[j], acc);
        sh_h[tid] = acc;
    }
    __syncthreads();

    if (tid < 5) {
        float acc = b2[tid];
        const float* w = W2 + tid * 32;
        #pragma unroll
        for (int o = 0; o < 32; ++o) acc = fmaf(sh_h[o], w[o], acc);
        sh_c[tid] = acc * c_poly[tid];
    }
    __syncthreads();

    const float c0 = sh_c[0], c1 = sh_c[1], c2 = sh_c[2],
                c3 = sh_c[3], c4 = sh_c[4];

    // ---- batched compute + store (data already in registers) ----
    op[tid]       = poly_eval4(e0, c0, c1, c2, c3, c4);
    op[tid + 256] = poly_eval4(e1, c0, c1, c2, c3, c4);
    op[tid + 512] = poly_eval4(e2, c0, c1, c2, c3, c4);
    op[tid + 768] = poly_eval4(e3, c0, c1, c2, c3, c4);
}

// ---------------------------------------------------------------------------
extern "C" void kernel_launch(void* const* d_in, const int* in_sizes, int n_in,
                              void* d_out, int out_size, void* d_ws, size_t ws_size,
                              hipStream_t stream) {
    const float* pp  = (const float*)d_in[0];   // [B,4]
    const float* eta = (const float*)d_in[1];   // [B,L]
    const float* W1  = (const float*)d_in[2];   // [32,64]
    const float* b1  = (const float*)d_in[3];   // [32]
    const float* W2  = (const float*)d_in[4];   // [5,32]
    const float* b2  = (const float*)d_in[5];   // [5]
    float* out   = (float*)d_out;
    double* part = (double*)d_ws;               // 2*NPART doubles (1 KB)

    k_part<<<NPART, 256, 0, stream>>>(pp, part);
    k_main<<<B, 256, 0, stream>>>(pp, eta, W1, b1, W2, b2, part, out);
}

// Round 9
// 33.742 us; speedup vs baseline: 2.4846x; 1.0011x over previous
//
#include <hip/hip_runtime.h>
#include <math.h>

static constexpr int B  = 4096;
static constexpr int L  = 4096;
static constexpr int NPART = 64;           // stats blocks; 64*256 = 16384 x-values

typedef float f4 __attribute__((ext_vector_type(4)));

__device__ __constant__ float c_ps_powers[16] = {
    -5.0f, -4.0f, -3.0f, -2.0f, -1.5f, -1.0f, -0.5f, 0.0f,
     0.5f,  2.0f,  0.33333334f, 3.0f, 0.25f, 4.0f, 0.2f, 5.0f};

__device__ __constant__ float c_poly[5] = {2.0f, 5.0f, 8.0f, 11.0f, 14.0f};

// hardware transcendentals: v_log_f32 (log2 x), v_exp_f32 (2^x)
__device__ __forceinline__ float hw_log2(float x) { return __builtin_amdgcn_logf(x); }
__device__ __forceinline__ float hw_exp2(float x) { return __builtin_amdgcn_exp2f(x); }

// ---------------------------------------------------------------------------
// Kernel 1: 64 blocks x 256 threads — one x-value per thread.
// part[0..63] = block sums, part[64..127] = block sumsqs (f64).
// ---------------------------------------------------------------------------
__global__ __launch_bounds__(256)
void k_part(const float* __restrict__ pp, double* __restrict__ part) {
    const int tid = threadIdx.x;
    const int g   = blockIdx.x * 256 + tid;       // 0 .. 16383
    const float lx = hw_log2(pp[g]);
    float sf = 0.0f, sf2 = 0.0f;
    #pragma unroll
    for (int p = 0; p < 16; ++p) {
        const float t = hw_exp2(c_ps_powers[p] * lx);
        sf  += t;
        sf2 = fmaf(t, t, sf2);
    }
    __shared__ double sh_s[256];
    __shared__ double sh_s2[256];
    sh_s[tid]  = (double)sf;
    sh_s2[tid] = (double)sf2;
    __syncthreads();
    for (int off = 128; off > 0; off >>= 1) {
        if (tid < off) {
            sh_s[tid]  += sh_s[tid + off];
            sh_s2[tid] += sh_s2[tid + off];
        }
        __syncthreads();
    }
    if (tid == 0) {
        part[blockIdx.x]         = sh_s[0];
        part[NPART + blockIdx.x] = sh_s2[0];
    }
}

// ---------------------------------------------------------------------------
// Kernel 2: one row per block.
//  - eta float4 loads issued first (latency hides under prologue; cached,
//    so eta stays L3-resident across replays)
//  - wave 1 reduces the 128 partials while wave 0 computes features
//  - features + MLP -> 5 scaled coefficients in LDS
//  - batched compute + NONTEMPORAL store (don't allocate out in L2/L3,
//    keeping eta resident):
//      dy = c0'*e + c1'*e^4 + c2'*e^7 + c3'*e^10 + c4'*e^13  (ck' = ck*p_k)
// ---------------------------------------------------------------------------
__device__ __forceinline__ float poly_eval(float e, float c0, float c1,
                                           float c2, float c3, float c4) {
    const float e3 = e * e * e;
    float w   = e;             // e^1
    float acc = c0 * w;
    w *= e3;                   // e^4
    acc = fmaf(c1, w, acc);
    w *= e3;                   // e^7
    acc = fmaf(c2, w, acc);
    w *= e3;                   // e^10
    acc = fmaf(c3, w, acc);
    w *= e3;                   // e^13
    acc = fmaf(c4, w, acc);
    return acc;
}

__device__ __forceinline__ f4 poly_eval4(f4 e, float c0, float c1,
                                         float c2, float c3, float c4) {
    f4 r;
    r.x = poly_eval(e.x, c0, c1, c2, c3, c4);
    r.y = poly_eval(e.y, c0, c1, c2, c3, c4);
    r.z = poly_eval(e.z, c0, c1, c2, c3, c4);
    r.w = poly_eval(e.w, c0, c1, c2, c3, c4);
    return r;
}

__global__ __launch_bounds__(256)
void k_main(const float* __restrict__ pp,  const float* __restrict__ eta,
            const float* __restrict__ W1,  const float* __restrict__ b1,
            const float* __restrict__ W2,  const float* __restrict__ b2,
            const double* __restrict__ part, float* __restrict__ out) {
    const int row = blockIdx.x;
    const int tid = threadIdx.x;

    // ---- issue all global loads up front ----
    const f4* ep = reinterpret_cast<const f4*>(eta + (size_t)row * L);
    f4*       op = reinterpret_cast<f4*>(out + (size_t)row * L);
    const f4 e0 = ep[tid];
    const f4 e1 = ep[tid + 256];
    const f4 e2 = ep[tid + 512];
    const f4 e3 = ep[tid + 768];

    __shared__ float sh_r[64];   // relu(norm) features (raw t before barrier)
    __shared__ float sh_h[32];   // hidden layer
    __shared__ float sh_c[8];    // scaled coefficients
    __shared__ float sh_stat[2]; // mean, inv_std

    // ---- wave 0: features (raw); wave 1: stats reduce — concurrent ----
    if (tid < 64) {
        const float x = pp[(row << 2) + (tid >> 4)];
        sh_r[tid] = hw_exp2(c_ps_powers[tid & 15] * hw_log2(x));
    } else if (tid < 128) {
        const int l = tid - 64;
        double s  = part[l];
        double s2 = part[NPART + l];
        #pragma unroll
        for (int m = 32; m > 0; m >>= 1) {
            s  += __shfl_xor(s,  m, 64);
            s2 += __shfl_xor(s2, m, 64);
        }
        if (l == 0) {
            const double n    = 262144.0;
            const double mean = s / n;
            const double var  = (s2 - n * mean * mean) / (n - 1.0);
            sh_stat[0] = (float)mean;
            sh_stat[1] = (float)(1.0 / sqrt(var));
        }
    }
    __syncthreads();

    if (tid < 64) {
        sh_r[tid] = fmaxf((sh_r[tid] - sh_stat[0]) * sh_stat[1], 0.0f);
    }
    __syncthreads();

    if (tid < 32) {
        float acc = b1[tid];
        const float* w = W1 + tid * 64;
        #pragma unroll
        for (int j = 0; j < 64; ++j) acc = fmaf(sh_r[j], w[j], acc);
        sh_h[tid] = acc;
    }
    __syncthreads();

    if (tid < 5) {
        float acc = b2[tid];
        const float* w = W2 + tid * 32;
        #pragma unroll
        for (int o = 0; o < 32; ++o) acc = fmaf(sh_h[o], w[o], acc);
        sh_c[tid] = acc * c_poly[tid];
    }
    __syncthreads();

    const float c0 = sh_c[0], c1 = sh_c[1], c2 = sh_c[2],
                c3 = sh_c[3], c4 = sh_c[4];

    // ---- batched compute + nontemporal store ----
    const f4 r0 = poly_eval4(e0, c0, c1, c2, c3, c4);
    const f4 r1 = poly_eval4(e1, c0, c1, c2, c3, c4);
    const f4 r2 = poly_eval4(e2, c0, c1, c2, c3, c4);
    const f4 r3 = poly_eval4(e3, c0, c1, c2, c3, c4);
    __builtin_nontemporal_store(r0, op + tid);
    __builtin_nontemporal_store(r1, op + tid + 256);
    __builtin_nontemporal_store(r2, op + tid + 512);
    __builtin_nontemporal_store(r3, op + tid + 768);
}

// ---------------------------------------------------------------------------
extern "C" void kernel_launch(void* const* d_in, const int* in_sizes, int n_in,
                              void* d_out, int out_size, void* d_ws, size_t ws_size,
                              hipStream_t stream) {
    const float* pp  = (const float*)d_in[0];   // [B,4]
    const float* eta = (const float*)d_in[1];   // [B,L]
    const float* W1  = (const float*)d_in[2];   // [32,64]
    const float* b1  = (const float*)d_in[3];   // [32]
    const float* W2  = (const float*)d_in[4];   // [5,32]
    const float* b2  = (const float*)d_in[5];   // [5]
    float* out   = (float*)d_out;
    double* part = (double*)d_ws;               // 2*NPART doubles (1 KB)

    k_part<<<NPART, 256, 0, stream>>>(pp, part);
    k_main<<<B, 256, 0, stream>>>(pp, eta, W1, b1, W2, b2, part, out);
}